// Round 8
// baseline (72.292 us; speedup 1.0000x reference)
//
#include <hip/hip_runtime.h>

// PhysicsInformedLoss on (16,3,1024,512) f32 y_hat + (16,2,1024,512) i32 x_in.
// R8: max TLP/MLP. One wave = one full row (lane owns 8 cols), RROWS=1 so all
// 20 VMEM/wave are independent (no serial rotation chain). 16384 waves / 4096
// blocks (16 blocks/CU queued). Bijective XCD swizzle: each XCD owns 2
// contiguous batches -> row reuse hits same-XCD L2. Two-kernel reduce
// (R5/R6 lesson: NO per-block device fences).

namespace {
constexpr int NXc  = 1024;
constexpr int NYc  = 512;
constexpr int NXYc = NXc * NYc;
constexpr int NBc  = 16;
constexpr int NTHR = 256;
constexpr int NACC = 10;
constexpr int NWAVE = NBc * NXc;            // 16384 waves, one per (b,row)
constexpr int NBLK  = NWAVE / (NTHR / 64);  // 4096 blocks
constexpr int NXCD  = 8;
constexpr int QX    = NBLK / NXCD;          // 512, exact
// acc: 0 s_div2, 1 s_resx2, 2 s_resy2, 3 n_interior,
//      4 s_noslip, 5 n_noslip, 6 s_inlet, 7 n_inlet, 8 s_outlet, 9 n_outlet
}

__global__ __launch_bounds__(NTHR) void pil_main(const float* __restrict__ y,
                                                 const int* __restrict__ xin,
                                                 float* __restrict__ partial) {
  constexpr double DXd = 0.26 / 1023.0;
  constexpr double DYd = 0.12 / 511.0;
  const float INV2DX = (float)(1.0 / (2.0 * DXd));
  const float INV2DY = (float)(1.0 / (2.0 * DYd));
  const float INVDX2 = (float)(1.0 / (DXd * DXd));
  const float INVDY2 = (float)(1.0 / (DYd * DYd));
  constexpr float NU = 1e-4f;
  constexpr float U_INLET = 0.1f;

  // bijective XCD swizzle: consecutive blockIdx round-robin XCDs; give each
  // XCD a contiguous chunk of the (b,i) space for L2 row-reuse.
  const int swz = (blockIdx.x % NXCD) * QX + blockIdx.x / NXCD;

  const int l  = threadIdx.x & 63;
  const int w  = (swz << 2) | (threadIdx.x >> 6);   // 0..16383
  const int i  = w & (NXc - 1);
  const int b  = w >> 10;
  const int jc = l << 3;                            // 8 cols per lane

  const float* __restrict__ ux = y + (size_t)b * 3 * NXYc;
  const float* __restrict__ uy = ux + NXYc;
  const float* __restrict__ pp = ux + 2 * NXYc;
  const int*   __restrict__ rp = xin + (size_t)(2 * b + 1) * NXYc;

  const int oc = i * NYc + jc;
  const int om = (i > 0       ? i - 1 : i) * NYc + jc;
  const int op = (i < NXc - 1 ? i + 1 : i) * NYc + jc;

  // 20 independent VMEM loads, one waitcnt before compute
  const float4 Pxl = *reinterpret_cast<const float4*>(ux + om);
  const float4 Pxh = *reinterpret_cast<const float4*>(ux + om + 4);
  const float4 Pyl = *reinterpret_cast<const float4*>(uy + om);
  const float4 Pyh = *reinterpret_cast<const float4*>(uy + om + 4);
  const float4 Ppl = *reinterpret_cast<const float4*>(pp + om);
  const float4 Pph = *reinterpret_cast<const float4*>(pp + om + 4);
  const float4 Cxl = *reinterpret_cast<const float4*>(ux + oc);
  const float4 Cxh = *reinterpret_cast<const float4*>(ux + oc + 4);
  const float4 Cyl = *reinterpret_cast<const float4*>(uy + oc);
  const float4 Cyh = *reinterpret_cast<const float4*>(uy + oc + 4);
  const float4 Cpl = *reinterpret_cast<const float4*>(pp + oc);
  const float4 Cph = *reinterpret_cast<const float4*>(pp + oc + 4);
  const float4 Nxl = *reinterpret_cast<const float4*>(ux + op);
  const float4 Nxh = *reinterpret_cast<const float4*>(ux + op + 4);
  const float4 Nyl = *reinterpret_cast<const float4*>(uy + op);
  const float4 Nyh = *reinterpret_cast<const float4*>(uy + op + 4);
  const float4 Npl = *reinterpret_cast<const float4*>(pp + op);
  const float4 Nph = *reinterpret_cast<const float4*>(pp + op + 4);
  const int4  rl   = *reinterpret_cast<const int4*>(rp + oc);
  const int4  rh   = *reinterpret_cast<const int4*>(rp + oc + 4);

  float a[NACC];
#pragma unroll
  for (int k = 0; k < NACC; ++k) a[k] = 0.f;

  const float cx[8]  = {Cxl.x, Cxl.y, Cxl.z, Cxl.w, Cxh.x, Cxh.y, Cxh.z, Cxh.w};
  const float cy_[8] = {Cyl.x, Cyl.y, Cyl.z, Cyl.w, Cyh.x, Cyh.y, Cyh.z, Cyh.w};
  const float cp_[8] = {Cpl.x, Cpl.y, Cpl.z, Cpl.w, Cph.x, Cph.y, Cph.z, Cph.w};
  const float pxA[8] = {Pxl.x, Pxl.y, Pxl.z, Pxl.w, Pxh.x, Pxh.y, Pxh.z, Pxh.w};
  const float pyA[8] = {Pyl.x, Pyl.y, Pyl.z, Pyl.w, Pyh.x, Pyh.y, Pyh.z, Pyh.w};
  const float ppA[8] = {Ppl.x, Ppl.y, Ppl.z, Ppl.w, Pph.x, Pph.y, Pph.z, Pph.w};
  const float nxA[8] = {Nxl.x, Nxl.y, Nxl.z, Nxl.w, Nxh.x, Nxh.y, Nxh.z, Nxh.w};
  const float nyA[8] = {Nyl.x, Nyl.y, Nyl.z, Nyl.w, Nyh.x, Nyh.y, Nyh.z, Nyh.w};
  const float npA[8] = {Npl.x, Npl.y, Npl.z, Npl.w, Nph.x, Nph.y, Nph.z, Nph.w};
  const int   rA[8]  = {rl.x, rl.y, rl.z, rl.w, rh.x, rh.y, rh.z, rh.w};

  // j-neighbors across lanes (edge lanes clamp; edge cols are never interior)
  float lxx = __shfl_up(cx[7], 1, 64);    if (l == 0)  lxx = cx[0];
  float rxx = __shfl_down(cx[0], 1, 64);  if (l == 63) rxx = cx[7];
  float lyy = __shfl_up(cy_[7], 1, 64);   if (l == 0)  lyy = cy_[0];
  float ryy = __shfl_down(cy_[0], 1, 64); if (l == 63) ryy = cy_[7];
  float lpp = __shfl_up(cp_[7], 1, 64);   if (l == 0)  lpp = cp_[0];
  float rpp = __shfl_down(cp_[0], 1, 64); if (l == 63) rpp = cp_[7];

  const bool irow = (i >= 1) & (i <= NXc - 2);

#pragma unroll
  for (int e = 0; e < 8; ++e) {
    const int   r    = rA[e];
    const float c_ux = cx[e], c_uy = cy_[e];
    const float uxm = (e == 0) ? lxx : cx[e - 1];
    const float uxp = (e == 7) ? rxx : cx[e + 1];
    const float uym = (e == 0) ? lyy : cy_[e - 1];
    const float uyp = (e == 7) ? ryy : cy_[e + 1];
    const float pm_ = (e == 0) ? lpp : cp_[e - 1];
    const float pq_ = (e == 7) ? rpp : cp_[e + 1];

    const float ddx_ux = (nxA[e] - pxA[e]) * INV2DX;
    const float ddy_ux = (uxp - uxm) * INV2DY;
    const float ddx_uy = (nyA[e] - pyA[e]) * INV2DX;
    const float ddy_uy = (uyp - uym) * INV2DY;

    const bool jedge = ((l == 0) & (e == 0)) | ((l == 63) & (e == 7));
    const bool interior = (r >= 1) & irow & (!jedge);
    if (interior) {
      const float dv    = ddx_ux + ddy_uy;
      const float d2xux = (nxA[e] - 2.f * c_ux + pxA[e]) * INVDX2;
      const float d2yux = (uxp - 2.f * c_ux + uxm) * INVDY2;
      const float d2xuy = (nyA[e] - 2.f * c_uy + pyA[e]) * INVDX2;
      const float d2yuy = (uyp - 2.f * c_uy + uym) * INVDY2;
      const float ddx_p = (npA[e] - ppA[e]) * INV2DX;
      const float ddy_p = (pq_ - pm_) * INV2DY;
      const float rx = c_ux * ddx_ux + c_uy * ddy_ux + ddx_p - NU * (d2xux + d2yux);
      const float ry = c_ux * ddx_uy + c_uy * ddy_uy + ddy_p - NU * (d2xuy + d2yuy);
      a[0] += dv * dv;
      a[1] += rx * rx;
      a[2] += ry * ry;
      a[3] += 1.f;
    }
    if ((r == 0) | (r == 2)) {
      a[4] += c_ux * c_ux + c_uy * c_uy;
      a[5] += 1.f;
    }
    if (r == 3) {
      const float d = c_ux - U_INLET;
      a[6] += d * d + c_uy * c_uy;
      a[7] += 1.f;
    }
    if (r == 4) {
      a[8] += ddx_ux * ddx_ux;
      a[9] += 1.f;
    }
  }

  // wave-64 shuffle reduction per accumulator
#pragma unroll
  for (int k = 0; k < NACC; ++k) {
    float v = a[k];
#pragma unroll
    for (int off = 32; off > 0; off >>= 1) v += __shfl_down(v, off, 64);
    a[k] = v;
  }

  __shared__ float sacc[NTHR / 64][NACC];
  const int lane = threadIdx.x & 63;
  const int wave = threadIdx.x >> 6;
  if (lane == 0) {
#pragma unroll
    for (int k = 0; k < NACC; ++k) sacc[wave][k] = a[k];
  }
  __syncthreads();
  if (threadIdx.x < NACC) {
    float s = 0.f;
#pragma unroll
    for (int ww = 0; ww < NTHR / 64; ++ww) s += sacc[ww][threadIdx.x];
    partial[threadIdx.x * NBLK + blockIdx.x] = s;   // SoA [NACC][NBLK]
  }
}

__global__ __launch_bounds__(NTHR) void pil_finalize(const float* __restrict__ partial,
                                                     float* __restrict__ out) {
  __shared__ double sw[NACC][NTHR / 64];
  const int t = threadIdx.x;
  const int lane = t & 63, wave = t >> 6;
#pragma unroll
  for (int k = 0; k < NACC; ++k) {
    double v = 0.0;
    for (int b = t; b < NBLK; b += NTHR) v += (double)partial[k * NBLK + b];
#pragma unroll
    for (int off = 32; off > 0; off >>= 1) v += __shfl_down(v, off, 64);
    if (lane == 0) sw[k][wave] = v;
  }
  __syncthreads();
  if (t == 0) {
    double acc[NACC];
#pragma unroll
    for (int k = 0; k < NACC; ++k) {
      double s = 0.0;
#pragma unroll
      for (int w = 0; w < NTHR / 64; ++w) s += sw[k][w];
      acc[k] = s;
    }
    const double l_cont = acc[0] / fmax(acc[3], 1.0);
    const double l_mom  = (acc[1] + acc[2]) / fmax(acc[3], 1.0);
    const double l_bc   = acc[4] / fmax(acc[5], 1.0)
                        + acc[6] / fmax(acc[7], 1.0)
                        + acc[8] / fmax(acc[9], 1.0);
    const double total  = 1.0 * l_cont + 0.1 * l_mom + 1.0 * l_bc;
    out[0] = (float)l_cont;
    out[1] = (float)l_mom;
    out[2] = (float)l_bc;
    out[3] = (float)total;
  }
}

extern "C" void kernel_launch(void* const* d_in, const int* in_sizes, int n_in,
                              void* d_out, int out_size, void* d_ws, size_t ws_size,
                              hipStream_t stream) {
  const float* y   = (const float*)d_in[0];   // y_hat (16,3,1024,512) f32
  const int*   xin = (const int*)d_in[1];     // x_in  (16,2,1024,512) i32
  float* partial   = (float*)d_ws;            // NACC*NBLK*4 = 160 KB

  pil_main<<<NBLK, NTHR, 0, stream>>>(y, xin, partial);
  pil_finalize<<<1, NTHR, 0, stream>>>(partial, (float*)d_out);
}

// Round 9
// 69.648 us; speedup vs baseline: 1.0380x; 1.0380x over previous
//
#include <hip/hip_runtime.h>

// PhysicsInformedLoss on (16,3,1024,512) f32 y_hat + (16,2,1024,512) i32 x_in.
// R9: LDS staging via __builtin_amdgcn_global_load_lds (16B/lane DMA, no VGPR
// round-trip). Block = 4 waves stages a 2-row tile (3 fields x 4 rows + 2
// region rows = 28 KB) -> 5 blocks/CU resident, ~140KB fills in flight per CU.
// Lane owns 4 cols -> conflict-free lane-consecutive ds_read_b128.
// 8192 blocks, bijective XCD swizzle (halo-sharing neighbors same L2).

namespace {
constexpr int NXc  = 1024;
constexpr int NYc  = 512;
constexpr int NXYc = NXc * NYc;
constexpr int NBc  = 16;
constexpr int NTHR = 256;
constexpr int NACC = 10;
constexpr int TR   = 2;                 // rows per block tile
constexpr int NCH  = NXc / TR;          // 512 chunks per batch
constexpr int NBLK = NBc * NCH;         // 8192 blocks
constexpr int NXCD = 8;
constexpr int QX   = NBLK / NXCD;       // 1024 (exact -> bijective swizzle)
// acc: 0 s_div2, 1 s_resx2, 2 s_resy2, 3 n_interior,
//      4 s_noslip, 5 n_noslip, 6 s_inlet, 7 n_inlet, 8 s_outlet, 9 n_outlet
}

__global__ __launch_bounds__(NTHR) void pil_main(const float* __restrict__ y,
                                                 const int* __restrict__ xin,
                                                 float* __restrict__ partial) {
  constexpr double DXd = 0.26 / 1023.0;
  constexpr double DYd = 0.12 / 511.0;
  const float INV2DX = (float)(1.0 / (2.0 * DXd));
  const float INV2DY = (float)(1.0 / (2.0 * DYd));
  const float INVDX2 = (float)(1.0 / (DXd * DXd));
  const float INVDY2 = (float)(1.0 / (DYd * DYd));
  constexpr float NU = 1e-4f;
  constexpr float U_INLET = 0.1f;

  __shared__ float lf[3][TR + 2][NYc];   // fields: rows i0-1 .. i0+TR
  __shared__ int   lr[TR][NYc];          // region: rows i0 .. i0+TR-1

  const int l   = threadIdx.x & 63;
  const int w   = threadIdx.x >> 6;
  const int swz = (blockIdx.x % NXCD) * QX + blockIdx.x / NXCD;  // bijective
  const int b   = swz >> 9;              // 512 chunks -> 9 bits
  const int i0  = (swz & (NCH - 1)) * TR;

  const float* __restrict__ ux = y + (size_t)b * 3 * NXYc;
  const float* __restrict__ uy = ux + NXYc;
  const float* __restrict__ pp = ux + 2 * NXYc;
  const int*   __restrict__ rp = xin + (size_t)(2 * b + 1) * NXYc;

  // ---- stage 28 x 1KB chunks into LDS (16B per lane, uniform LDS base) ----
  for (int c = w; c < 28; c += 4) {
    const float* g;
    float* d;
    if (c < 24) {                        // field chunks
      const int f  = c >> 3;             // 0..2
      const int rw = (c & 7) >> 1;       // 0..3
      const int h  = c & 1;              // half-row
      int gi = i0 - 1 + rw;
      gi = gi < 0 ? 0 : (gi > NXc - 1 ? NXc - 1 : gi);   // edge clamp
      const float* base = (f == 0) ? ux : ((f == 1) ? uy : pp);
      g = base + gi * NYc + h * 256 + l * 4;
      d = &lf[f][rw][h * 256];
    } else {                             // region chunks
      const int cc = c - 24, rw = cc >> 1, h = cc & 1;
      g = (const float*)(rp + (i0 + rw) * NYc + h * 256 + l * 4);
      d = (float*)&lr[rw][h * 256];
    }
    __builtin_amdgcn_global_load_lds(
        (const __attribute__((address_space(1))) void*)g,
        (__attribute__((address_space(3))) void*)d, 16, 0, 0);
  }
  __syncthreads();   // compiler emits s_waitcnt vmcnt(0) before s_barrier

  // ---- compute: wave w -> tile row r = w>>1, half h = w&1; 4 cols/lane ----
  const int r  = w >> 1;
  const int h  = w & 1;
  const int i  = i0 + r;
  const int j0 = h * 256 + (l << 2);

  float a[NACC];
#pragma unroll
  for (int k = 0; k < NACC; ++k) a[k] = 0.f;

  const float4 Cx = *reinterpret_cast<const float4*>(&lf[0][r + 1][j0]);
  const float4 Cy = *reinterpret_cast<const float4*>(&lf[1][r + 1][j0]);
  const float4 Cp = *reinterpret_cast<const float4*>(&lf[2][r + 1][j0]);
  const float4 Px = *reinterpret_cast<const float4*>(&lf[0][r][j0]);
  const float4 Py = *reinterpret_cast<const float4*>(&lf[1][r][j0]);
  const float4 Pp = *reinterpret_cast<const float4*>(&lf[2][r][j0]);
  const float4 Nx = *reinterpret_cast<const float4*>(&lf[0][r + 2][j0]);
  const float4 Ny = *reinterpret_cast<const float4*>(&lf[1][r + 2][j0]);
  const float4 Np = *reinterpret_cast<const float4*>(&lf[2][r + 2][j0]);
  const int4   R4 = *reinterpret_cast<const int4*>(&lr[r][j0]);

  const int jm = (j0 == 0) ? 0 : j0 - 1;          // global edge clamp
  const int jp = (j0 + 4 > NYc - 1) ? NYc - 1 : j0 + 4;
  const float lx = lf[0][r + 1][jm], rx = lf[0][r + 1][jp];
  const float ly = lf[1][r + 1][jm], ry = lf[1][r + 1][jp];
  const float lq = lf[2][r + 1][jm], rq = lf[2][r + 1][jp];

  const float cx[6]  = {lx, Cx.x, Cx.y, Cx.z, Cx.w, rx};
  const float cy_[6] = {ly, Cy.x, Cy.y, Cy.z, Cy.w, ry};
  const float cp_[6] = {lq, Cp.x, Cp.y, Cp.z, Cp.w, rq};
  const float pxA[4] = {Px.x, Px.y, Px.z, Px.w};
  const float pyA[4] = {Py.x, Py.y, Py.z, Py.w};
  const float ppA[4] = {Pp.x, Pp.y, Pp.z, Pp.w};
  const float nxA[4] = {Nx.x, Nx.y, Nx.z, Nx.w};
  const float nyA[4] = {Ny.x, Ny.y, Ny.z, Ny.w};
  const float npA[4] = {Np.x, Np.y, Np.z, Np.w};
  const int   rA[4]  = {R4.x, R4.y, R4.z, R4.w};

  const bool irow = (i >= 1) & (i <= NXc - 2);

#pragma unroll
  for (int e = 0; e < 4; ++e) {
    const int   rg   = rA[e];
    const float c_ux = cx[e + 1], c_uy = cy_[e + 1];
    const float uxm = cx[e],      uxp = cx[e + 2];
    const float uym = cy_[e],     uyp = cy_[e + 2];
    const float pm_ = cp_[e],     pq_ = cp_[e + 2];

    const float ddx_ux = (nxA[e] - pxA[e]) * INV2DX;
    const float ddy_ux = (uxp - uxm) * INV2DY;
    const float ddx_uy = (nyA[e] - pyA[e]) * INV2DX;
    const float ddy_uy = (uyp - uym) * INV2DY;

    const int j = j0 + e;
    const bool jedge = (j == 0) | (j == NYc - 1);
    const bool interior = (rg >= 1) & irow & (!jedge);
    if (interior) {
      const float dv    = ddx_ux + ddy_uy;
      const float d2xux = (nxA[e] - 2.f * c_ux + pxA[e]) * INVDX2;
      const float d2yux = (uxp - 2.f * c_ux + uxm) * INVDY2;
      const float d2xuy = (nyA[e] - 2.f * c_uy + pyA[e]) * INVDX2;
      const float d2yuy = (uyp - 2.f * c_uy + uym) * INVDY2;
      const float ddx_p = (npA[e] - ppA[e]) * INV2DX;
      const float ddy_p = (pq_ - pm_) * INV2DY;
      const float rxx = c_ux * ddx_ux + c_uy * ddy_ux + ddx_p - NU * (d2xux + d2yux);
      const float ryy = c_ux * ddx_uy + c_uy * ddy_uy + ddy_p - NU * (d2xuy + d2yuy);
      a[0] += dv * dv;
      a[1] += rxx * rxx;
      a[2] += ryy * ryy;
      a[3] += 1.f;
    }
    if ((rg == 0) | (rg == 2)) {         // noslip = obstacle | wall
      a[4] += c_ux * c_ux + c_uy * c_uy;
      a[5] += 1.f;
    }
    if (rg == 3) {                        // inlet
      const float d = c_ux - U_INLET;
      a[6] += d * d + c_uy * c_uy;
      a[7] += 1.f;
    }
    if (rg == 4) {                        // outlet
      a[8] += ddx_ux * ddx_ux;
      a[9] += 1.f;
    }
  }

  // wave-64 shuffle reduction per accumulator
#pragma unroll
  for (int k = 0; k < NACC; ++k) {
    float v = a[k];
#pragma unroll
    for (int off = 32; off > 0; off >>= 1) v += __shfl_down(v, off, 64);
    a[k] = v;
  }

  __shared__ float sacc[NTHR / 64][NACC];
  if (l == 0) {
#pragma unroll
    for (int k = 0; k < NACC; ++k) sacc[w][k] = a[k];
  }
  __syncthreads();
  if (threadIdx.x < NACC) {
    float s = 0.f;
#pragma unroll
    for (int ww = 0; ww < NTHR / 64; ++ww) s += sacc[ww][threadIdx.x];
    partial[threadIdx.x * NBLK + blockIdx.x] = s;   // SoA [NACC][NBLK]
  }
}

__global__ __launch_bounds__(NTHR) void pil_finalize(const float* __restrict__ partial,
                                                     float* __restrict__ out) {
  __shared__ double sw[NACC][NTHR / 64];
  const int t = threadIdx.x;
  const int lane = t & 63, wave = t >> 6;
#pragma unroll
  for (int k = 0; k < NACC; ++k) {
    double v = 0.0;
    const float4* p4 = reinterpret_cast<const float4*>(partial + (size_t)k * NBLK);
    for (int bb = t; bb < NBLK / 4; bb += NTHR) {
      const float4 q = p4[bb];
      v += (double)q.x + (double)q.y + (double)q.z + (double)q.w;
    }
#pragma unroll
    for (int off = 32; off > 0; off >>= 1) v += __shfl_down(v, off, 64);
    if (lane == 0) sw[k][wave] = v;
  }
  __syncthreads();
  if (t == 0) {
    double acc[NACC];
#pragma unroll
    for (int k = 0; k < NACC; ++k) {
      double s = 0.0;
#pragma unroll
      for (int ww = 0; ww < NTHR / 64; ++ww) s += sw[k][ww];
      acc[k] = s;
    }
    const double l_cont = acc[0] / fmax(acc[3], 1.0);
    const double l_mom  = (acc[1] + acc[2]) / fmax(acc[3], 1.0);
    const double l_bc   = acc[4] / fmax(acc[5], 1.0)
                        + acc[6] / fmax(acc[7], 1.0)
                        + acc[8] / fmax(acc[9], 1.0);
    const double total  = 1.0 * l_cont + 0.1 * l_mom + 1.0 * l_bc;
    out[0] = (float)l_cont;
    out[1] = (float)l_mom;
    out[2] = (float)l_bc;
    out[3] = (float)total;
  }
}

extern "C" void kernel_launch(void* const* d_in, const int* in_sizes, int n_in,
                              void* d_out, int out_size, void* d_ws, size_t ws_size,
                              hipStream_t stream) {
  const float* y   = (const float*)d_in[0];   // y_hat (16,3,1024,512) f32
  const int*   xin = (const int*)d_in[1];     // x_in  (16,2,1024,512) i32
  float* partial   = (float*)d_ws;            // NACC*NBLK*4 = 320 KB

  pil_main<<<NBLK, NTHR, 0, stream>>>(y, xin, partial);
  pil_finalize<<<1, NTHR, 0, stream>>>(partial, (float*)d_out);
}

// Round 10
// 47.156 us; speedup vs baseline: 1.5330x; 1.4770x over previous
//
#include <hip/hip_runtime.h>

// PhysicsInformedLoss on (16,3,1024,512) f32 y_hat + (16,2,1024,512) i32 x_in.
// R10: global_load_lds DMA staging with amortized halo. Block = 512 thr
// (8 waves) stages 10 field rows (3 fields x 10 x 2KB = 60KB static LDS) for
// 8 compute rows; region codes load straight to VGPR (overlap DMA). Staged
// bytes = 158MB (vs R9's 229MB). 2048 blocks, 2 blocks/CU resident.
// R5/R6 lesson: no per-block device fences -> two-kernel reduce.

namespace {
constexpr int NXc  = 1024;
constexpr int NYc  = 512;
constexpr int NXYc = NXc * NYc;
constexpr int NBc  = 16;
constexpr int NTHR = 512;               // 8 waves
constexpr int NACC = 10;
constexpr int TR   = 8;                 // compute rows per block
constexpr int NCH  = NXc / TR;          // 128 chunks per batch
constexpr int NBLK = NBc * NCH;         // 2048 blocks
constexpr int NXCD = 8;
constexpr int QX   = NBLK / NXCD;       // 256 (exact -> bijective swizzle)
// acc: 0 s_div2, 1 s_resx2, 2 s_resy2, 3 n_interior,
//      4 s_noslip, 5 n_noslip, 6 s_inlet, 7 n_inlet, 8 s_outlet, 9 n_outlet
}

__global__ __launch_bounds__(NTHR) void pil_main(const float* __restrict__ y,
                                                 const int* __restrict__ xin,
                                                 float* __restrict__ partial) {
  constexpr double DXd = 0.26 / 1023.0;
  constexpr double DYd = 0.12 / 511.0;
  const float INV2DX = (float)(1.0 / (2.0 * DXd));
  const float INV2DY = (float)(1.0 / (2.0 * DYd));
  const float INVDX2 = (float)(1.0 / (DXd * DXd));
  const float INVDY2 = (float)(1.0 / (DYd * DYd));
  constexpr float NU = 1e-4f;
  constexpr float U_INLET = 0.1f;

  __shared__ float lf[3][TR + 2][NYc];   // 3 fields, rows i0-1 .. i0+TR (60KB)

  const int l   = threadIdx.x & 63;
  const int w   = threadIdx.x >> 6;      // wave 0..7
  const int swz = (blockIdx.x % NXCD) * QX + blockIdx.x / NXCD;  // bijective
  const int b   = swz >> 7;              // 128 chunks -> 7 bits
  const int i0  = (swz & (NCH - 1)) * TR;

  const float* __restrict__ ux = y + (size_t)b * 3 * NXYc;
  const float* __restrict__ uy = ux + NXYc;
  const float* __restrict__ pp = ux + 2 * NXYc;
  const int*   __restrict__ rp = xin + (size_t)(2 * b + 1) * NXYc;

  // ---- DMA-stage 60 x 1KB chunks (3 fields x 10 rows x 2 halves) ----
  // chunk c: f = c/20, rw = (c%20)>>1, h = c&1; wave-uniform addressing.
  for (int c = w; c < 60; c += 8) {
    const int f  = c / 20;
    const int cc = c % 20;
    const int rw = cc >> 1;
    const int h  = cc & 1;
    int gi = i0 - 1 + rw;
    gi = gi < 0 ? 0 : (gi > NXc - 1 ? NXc - 1 : gi);   // edge clamp
    const float* base = (f == 0) ? ux : ((f == 1) ? uy : pp);
    const float* g = base + gi * NYc + h * 256 + l * 4;
    float* d = &lf[f][rw][h * 256];
    __builtin_amdgcn_global_load_lds(
        (const __attribute__((address_space(1))) void*)g,
        (__attribute__((address_space(3))) void*)d, 16, 0, 0);
  }

  // region codes for this wave's row -> VGPRs (overlaps the DMA)
  const int i = i0 + w;                   // global row this wave computes
  const int4 R0 = *reinterpret_cast<const int4*>(rp + i * NYc + (l << 2));
  const int4 R1 = *reinterpret_cast<const int4*>(rp + i * NYc + 256 + (l << 2));

  __syncthreads();   // vmcnt drain + barrier: LDS tile ready

  float a[NACC];
#pragma unroll
  for (int k = 0; k < NACC; ++k) a[k] = 0.f;

  const bool irow = (i >= 1) & (i <= NXc - 2);

#pragma unroll
  for (int h = 0; h < 2; ++h) {
    const int j0 = h * 256 + (l << 2);

    const float4 Cx = *reinterpret_cast<const float4*>(&lf[0][w + 1][j0]);
    const float4 Cy = *reinterpret_cast<const float4*>(&lf[1][w + 1][j0]);
    const float4 Cp = *reinterpret_cast<const float4*>(&lf[2][w + 1][j0]);
    const float4 Px = *reinterpret_cast<const float4*>(&lf[0][w][j0]);
    const float4 Py = *reinterpret_cast<const float4*>(&lf[1][w][j0]);
    const float4 Pp = *reinterpret_cast<const float4*>(&lf[2][w][j0]);
    const float4 Nx = *reinterpret_cast<const float4*>(&lf[0][w + 2][j0]);
    const float4 Ny = *reinterpret_cast<const float4*>(&lf[1][w + 2][j0]);
    const float4 Np = *reinterpret_cast<const float4*>(&lf[2][w + 2][j0]);
    const int4   R4 = h ? R1 : R0;

    const int jm = (j0 == 0) ? 0 : j0 - 1;              // global edge clamp
    const int jp = (j0 + 4 > NYc - 1) ? NYc - 1 : j0 + 4;
    const float lx = lf[0][w + 1][jm], rx = lf[0][w + 1][jp];
    const float ly = lf[1][w + 1][jm], ry = lf[1][w + 1][jp];
    const float lq = lf[2][w + 1][jm], rq = lf[2][w + 1][jp];

    const float cx[6]  = {lx, Cx.x, Cx.y, Cx.z, Cx.w, rx};
    const float cy_[6] = {ly, Cy.x, Cy.y, Cy.z, Cy.w, ry};
    const float cp_[6] = {lq, Cp.x, Cp.y, Cp.z, Cp.w, rq};
    const float pxA[4] = {Px.x, Px.y, Px.z, Px.w};
    const float pyA[4] = {Py.x, Py.y, Py.z, Py.w};
    const float ppA[4] = {Pp.x, Pp.y, Pp.z, Pp.w};
    const float nxA[4] = {Nx.x, Nx.y, Nx.z, Nx.w};
    const float nyA[4] = {Ny.x, Ny.y, Ny.z, Ny.w};
    const float npA[4] = {Np.x, Np.y, Np.z, Np.w};
    const int   rA[4]  = {R4.x, R4.y, R4.z, R4.w};

#pragma unroll
    for (int e = 0; e < 4; ++e) {
      const int   rg   = rA[e];
      const float c_ux = cx[e + 1], c_uy = cy_[e + 1];
      const float uxm = cx[e],      uxp = cx[e + 2];
      const float uym = cy_[e],     uyp = cy_[e + 2];
      const float pm_ = cp_[e],     pq_ = cp_[e + 2];

      const float ddx_ux = (nxA[e] - pxA[e]) * INV2DX;
      const float ddy_ux = (uxp - uxm) * INV2DY;
      const float ddx_uy = (nyA[e] - pyA[e]) * INV2DX;
      const float ddy_uy = (uyp - uym) * INV2DY;

      const int j = j0 + e;
      const bool jedge = (j == 0) | (j == NYc - 1);
      const bool interior = (rg >= 1) & irow & (!jedge);
      if (interior) {
        const float dv    = ddx_ux + ddy_uy;
        const float d2xux = (nxA[e] - 2.f * c_ux + pxA[e]) * INVDX2;
        const float d2yux = (uxp - 2.f * c_ux + uxm) * INVDY2;
        const float d2xuy = (nyA[e] - 2.f * c_uy + pyA[e]) * INVDX2;
        const float d2yuy = (uyp - 2.f * c_uy + uym) * INVDY2;
        const float ddx_p = (npA[e] - ppA[e]) * INV2DX;
        const float ddy_p = (pq_ - pm_) * INV2DY;
        const float rxv = c_ux * ddx_ux + c_uy * ddy_ux + ddx_p - NU * (d2xux + d2yux);
        const float ryv = c_ux * ddx_uy + c_uy * ddy_uy + ddy_p - NU * (d2xuy + d2yuy);
        a[0] += dv * dv;
        a[1] += rxv * rxv;
        a[2] += ryv * ryv;
        a[3] += 1.f;
      }
      if ((rg == 0) | (rg == 2)) {         // noslip = obstacle | wall
        a[4] += c_ux * c_ux + c_uy * c_uy;
        a[5] += 1.f;
      }
      if (rg == 3) {                        // inlet
        const float d = c_ux - U_INLET;
        a[6] += d * d + c_uy * c_uy;
        a[7] += 1.f;
      }
      if (rg == 4) {                        // outlet
        a[8] += ddx_ux * ddx_ux;
        a[9] += 1.f;
      }
    }
  }

  // wave-64 shuffle reduction per accumulator
#pragma unroll
  for (int k = 0; k < NACC; ++k) {
    float v = a[k];
#pragma unroll
    for (int off = 32; off > 0; off >>= 1) v += __shfl_down(v, off, 64);
    a[k] = v;
  }

  __shared__ float sacc[NTHR / 64][NACC];
  if (l == 0) {
#pragma unroll
    for (int k = 0; k < NACC; ++k) sacc[w][k] = a[k];
  }
  __syncthreads();
  if (threadIdx.x < NACC) {
    float s = 0.f;
#pragma unroll
    for (int ww = 0; ww < NTHR / 64; ++ww) s += sacc[ww][threadIdx.x];
    partial[threadIdx.x * NBLK + blockIdx.x] = s;   // SoA [NACC][NBLK]
  }
}

__global__ __launch_bounds__(256) void pil_finalize(const float* __restrict__ partial,
                                                    float* __restrict__ out) {
  __shared__ double sw[NACC][4];
  const int t = threadIdx.x;
  const int lane = t & 63, wave = t >> 6;
#pragma unroll
  for (int k = 0; k < NACC; ++k) {
    double v = 0.0;
    const float4* p4 = reinterpret_cast<const float4*>(partial + (size_t)k * NBLK);
    for (int bb = t; bb < NBLK / 4; bb += 256) {
      const float4 q = p4[bb];
      v += (double)q.x + (double)q.y + (double)q.z + (double)q.w;
    }
#pragma unroll
    for (int off = 32; off > 0; off >>= 1) v += __shfl_down(v, off, 64);
    if (lane == 0) sw[k][wave] = v;
  }
  __syncthreads();
  if (t == 0) {
    double acc[NACC];
#pragma unroll
    for (int k = 0; k < NACC; ++k) {
      double s = 0.0;
#pragma unroll
      for (int ww = 0; ww < 4; ++ww) s += sw[k][ww];
      acc[k] = s;
    }
    const double l_cont = acc[0] / fmax(acc[3], 1.0);
    const double l_mom  = (acc[1] + acc[2]) / fmax(acc[3], 1.0);
    const double l_bc   = acc[4] / fmax(acc[5], 1.0)
                        + acc[6] / fmax(acc[7], 1.0)
                        + acc[8] / fmax(acc[9], 1.0);
    const double total  = 1.0 * l_cont + 0.1 * l_mom + 1.0 * l_bc;
    out[0] = (float)l_cont;
    out[1] = (float)l_mom;
    out[2] = (float)l_bc;
    out[3] = (float)total;
  }
}

extern "C" void kernel_launch(void* const* d_in, const int* in_sizes, int n_in,
                              void* d_out, int out_size, void* d_ws, size_t ws_size,
                              hipStream_t stream) {
  const float* y   = (const float*)d_in[0];   // y_hat (16,3,1024,512) f32
  const int*   xin = (const int*)d_in[1];     // x_in  (16,2,1024,512) i32
  float* partial   = (float*)d_ws;            // NACC*NBLK*4 = 80 KB

  pil_main<<<NBLK, NTHR, 0, stream>>>(y, xin, partial);
  pil_finalize<<<1, 256, 0, stream>>>(partial, (float*)d_out);
}